// Round 1
// baseline (109.503 us; speedup 1.0000x reference)
//
#include <hip/hip_runtime.h>
#include <hip/hip_bf16.h>

typedef __attribute__((ext_vector_type(8))) short short8;
typedef __attribute__((ext_vector_type(4))) float f32x4;

#define N 8192
#define D 256
#define INV_T 10.0f
#define EPSN 1e-8f

__device__ __forceinline__ unsigned short f2bf(float x) {
  unsigned int u = __float_as_uint(x);
  u += 0x7fffu + ((u >> 16) & 1u);
  return (unsigned short)(u >> 16);
}

__device__ __forceinline__ void async16(void* lds, const void* g) {
  __builtin_amdgcn_global_load_lds(
      (const __attribute__((address_space(1))) void*)g,
      (__attribute__((address_space(3))) void*)lds,
      16, 0, 0);
}

// One wave per row: compute fp32 norm, write bf16 normalized row + norm.
__global__ __launch_bounds__(256) void normalize_k(const float* __restrict__ feats,
                                                   unsigned short* __restrict__ fn,
                                                   float* __restrict__ norms) {
  int row = blockIdx.x * 4 + (threadIdx.x >> 6);
  int lane = threadIdx.x & 63;
  float4 v = ((const float4*)(feats + (size_t)row * D))[lane];
  float ss = v.x * v.x + v.y * v.y + v.z * v.z + v.w * v.w;
#pragma unroll
  for (int off = 32; off; off >>= 1) ss += __shfl_xor(ss, off, 64);
  float nrm = sqrtf(ss);
  float inv = 1.0f / fmaxf(nrm, EPSN);
  uint2 o;
  o.x = (unsigned)f2bf(v.x * inv) | ((unsigned)f2bf(v.y * inv) << 16);
  o.y = (unsigned)f2bf(v.z * inv) | ((unsigned)f2bf(v.w * inv) << 16);
  ((uint2*)(fn + (size_t)row * D))[lane] = o;
  if (lane == 0) norms[row] = nrm;
}

// pos[i] = dot(feats[i], feats[(i+N/2)%N]) / (max(ni,eps)*max(nj,eps)) / T, fp32.
__global__ __launch_bounds__(256) void pos_k(const float* __restrict__ feats,
                                             const float* __restrict__ norms,
                                             float* __restrict__ pos) {
  int i = blockIdx.x * 4 + (threadIdx.x >> 6);
  int lane = threadIdx.x & 63;
  int j = (i + (N / 2)) & (N - 1);
  float4 a = ((const float4*)(feats + (size_t)i * D))[lane];
  float4 b = ((const float4*)(feats + (size_t)j * D))[lane];
  float d = a.x * b.x + a.y * b.y + a.z * b.z + a.w * b.w;
#pragma unroll
  for (int off = 32; off; off >>= 1) d += __shfl_xor(d, off, 64);
  if (lane == 0)
    pos[i] = d / (fmaxf(norms[i], EPSN) * fmaxf(norms[j], EPSN)) * INV_T;
}

// Fused GEMM (C = fn * fn^T / T) + exp(C - 10) row-sum accumulation.
// 128x128 tile, BK=64, 4 waves (2x2), 16x16x32 bf16 MFMA, 4x4 frags/wave.
__global__ __launch_bounds__(256) void gemm_lse(const unsigned short* __restrict__ fn,
                                                float* __restrict__ rowsum) {
  __shared__ unsigned short As[128 * 64];
  __shared__ unsigned short Bs[128 * 64];
  __shared__ float lrow[128];
  int tid = threadIdx.x;
  int wave = tid >> 6, lane = tid & 63;
  int wm = wave >> 1, wn = wave & 1;
  int hi = lane >> 4, lo = lane & 15;
  int bm = blockIdx.x >> 6, bn = blockIdx.x & 63;

  if (tid < 128) lrow[tid] = 0.0f;

  f32x4 acc[4][4];
#pragma unroll
  for (int m = 0; m < 4; ++m)
#pragma unroll
    for (int n = 0; n < 4; ++n) acc[m][n] = (f32x4){0.f, 0.f, 0.f, 0.f};

  const char* fb = (const char*)fn;
  // staging geometry: each wave stages bytes [wave*4K, wave*4K+4K) of each tile,
  // 4 insts x (64 lanes x 16B). LDS tile is linear [128 rows][64 k] bf16 (128B rows).
  int o = wave * 4096 + lane * 16;
  int r0 = o >> 7;      // row within tile (inst adds 8 rows)
  int cb = o & 127;     // byte within row

#pragma unroll 1
  for (int kt = 0; kt < 4; ++kt) {
    __syncthreads();  // previous tile fully consumed (also covers lrow init)
    int k0b = kt * 128;  // BK*2 bytes along K
#pragma unroll
    for (int inst = 0; inst < 4; ++inst) {
      const char* ga = fb + (size_t)(bm * 128 + r0 + inst * 8) * (D * 2) + k0b + cb;
      const char* gb = fb + (size_t)(bn * 128 + r0 + inst * 8) * (D * 2) + k0b + cb;
      async16(&As[wave * 2048 + inst * 512], ga);
      async16(&Bs[wave * 2048 + inst * 512], gb);
    }
    __syncthreads();  // drains vmcnt: tiles ready
#pragma unroll
    for (int ks = 0; ks < 2; ++ks) {
      int kb = ks * 32 + hi * 8;
      short8 af[4], bfr[4];
#pragma unroll
      for (int m = 0; m < 4; ++m)
        af[m] = *(const short8*)&As[(wm * 64 + m * 16 + lo) * 64 + kb];
#pragma unroll
      for (int n = 0; n < 4; ++n)
        bfr[n] = *(const short8*)&Bs[(wn * 64 + n * 16 + lo) * 64 + kb];
#pragma unroll
      for (int m = 0; m < 4; ++m)
#pragma unroll
        for (int n = 0; n < 4; ++n)
          acc[m][n] = __builtin_amdgcn_mfma_f32_16x16x32_bf16(af[m], bfr[n], acc[m][n], 0, 0, 0);
    }
  }

  // Epilogue: e = exp(sim/T - 10), skip true diagonal, per-row reduce.
  // C frag layout: col = lane&15, row = (lane>>4)*4 + reg.
#pragma unroll
  for (int m = 0; m < 4; ++m) {
#pragma unroll
    for (int j = 0; j < 4; ++j) {
      int lr = wm * 64 + m * 16 + hi * 4 + j;
      int grow = bm * 128 + lr;
      float v = 0.f;
#pragma unroll
      for (int n = 0; n < 4; ++n) {
        int gcol = bn * 128 + wn * 64 + n * 16 + lo;
        float e = __expf(acc[m][n][j] * INV_T - 10.0f);
        v += (grow == gcol) ? 0.f : e;
      }
#pragma unroll
      for (int off = 1; off < 16; off <<= 1) v += __shfl_xor(v, off, 64);
      if (lo == 0) atomicAdd(&lrow[lr], v);
    }
  }
  __syncthreads();
  if (tid < 128) atomicAdd(&rowsum[bm * 128 + tid], lrow[tid]);
}

__global__ __launch_bounds__(256) void final_k(const float* __restrict__ rowsum,
                                               const float* __restrict__ pos,
                                               float* __restrict__ out) {
  int tid = threadIdx.x;
  float s = 0.f;
  for (int i = tid; i < N; i += 256) s += 10.0f + logf(rowsum[i]) - pos[i];
#pragma unroll
  for (int off = 32; off; off >>= 1) s += __shfl_xor(s, off, 64);
  __shared__ float red[4];
  if ((tid & 63) == 0) red[tid >> 6] = s;
  __syncthreads();
  if (tid == 0) out[0] = (red[0] + red[1] + red[2] + red[3]) * (1.0f / N);
}

extern "C" void kernel_launch(void* const* d_in, const int* in_sizes, int n_in,
                              void* d_out, int out_size, void* d_ws, size_t ws_size,
                              hipStream_t stream) {
  const float* feats = (const float*)d_in[0];
  float* out = (float*)d_out;
  char* ws = (char*)d_ws;
  unsigned short* fn = (unsigned short*)ws;                    // 4 MB bf16 normalized feats
  float* norms = (float*)(ws + 4 * 1024 * 1024);               // 32 KB
  float* pos = (float*)(ws + 4 * 1024 * 1024 + 32 * 1024);     // 32 KB
  float* rowsum = (float*)(ws + 4 * 1024 * 1024 + 64 * 1024);  // 32 KB

  hipMemsetAsync(rowsum, 0, N * sizeof(float), stream);
  normalize_k<<<N / 4, 256, 0, stream>>>(feats, fn, norms);
  pos_k<<<N / 4, 256, 0, stream>>>(feats, norms, pos);
  gemm_lse<<<64 * 64, 256, 0, stream>>>(fn, rowsum);
  final_k<<<1, 256, 0, stream>>>(rowsum, pos, out);
}

// Round 2
// 92.814 us; speedup vs baseline: 1.1798x; 1.1798x over previous
//
#include <hip/hip_runtime.h>
#include <hip/hip_bf16.h>

typedef __attribute__((ext_vector_type(8))) short short8;
typedef __attribute__((ext_vector_type(4))) float f32x4;

#define N 8192
#define D 256
#define INV_T 10.0f
#define EPSN 1e-8f

__device__ __forceinline__ unsigned short f2bf(float x) {
  unsigned int u = __float_as_uint(x);
  u += 0x7fffu + ((u >> 16) & 1u);
  return (unsigned short)(u >> 16);
}

__device__ __forceinline__ void async16(void* lds, const void* g) {
  __builtin_amdgcn_global_load_lds(
      (const __attribute__((address_space(1))) void*)g,
      (__attribute__((address_space(3))) void*)lds,
      16, 0, 0);
}

// One wave per row: fp32 norm, bf16 normalized row + norm. Also zeroes rowsum.
__global__ __launch_bounds__(256) void normalize_k(const float* __restrict__ feats,
                                                   unsigned short* __restrict__ fn,
                                                   float* __restrict__ norms,
                                                   float* __restrict__ rowsum) {
  int row = blockIdx.x * 4 + (threadIdx.x >> 6);
  int lane = threadIdx.x & 63;
  if (threadIdx.x < 4) rowsum[blockIdx.x * 4 + threadIdx.x] = 0.0f;
  float4 v = ((const float4*)(feats + (size_t)row * D))[lane];
  float ss = v.x * v.x + v.y * v.y + v.z * v.z + v.w * v.w;
#pragma unroll
  for (int off = 32; off; off >>= 1) ss += __shfl_xor(ss, off, 64);
  float nrm = sqrtf(ss);
  float inv = 1.0f / fmaxf(nrm, EPSN);
  uint2 o;
  o.x = (unsigned)f2bf(v.x * inv) | ((unsigned)f2bf(v.y * inv) << 16);
  o.y = (unsigned)f2bf(v.z * inv) | ((unsigned)f2bf(v.w * inv) << 16);
  ((uint2*)(fn + (size_t)row * D))[lane] = o;
  if (lane == 0) norms[row] = nrm;
}

// pos[i] = dot(feats[i], feats[(i+N/2)%N]) / (max(ni,eps)*max(nj,eps)) / T, fp32.
__global__ __launch_bounds__(256) void pos_k(const float* __restrict__ feats,
                                             const float* __restrict__ norms,
                                             float* __restrict__ pos) {
  int i = blockIdx.x * 4 + (threadIdx.x >> 6);
  int lane = threadIdx.x & 63;
  int j = (i + (N / 2)) & (N - 1);
  float4 a = ((const float4*)(feats + (size_t)i * D))[lane];
  float4 b = ((const float4*)(feats + (size_t)j * D))[lane];
  float d = a.x * b.x + a.y * b.y + a.z * b.z + a.w * b.w;
#pragma unroll
  for (int off = 32; off; off >>= 1) d += __shfl_xor(d, off, 64);
  if (lane == 0)
    pos[i] = d / (fmaxf(norms[i], EPSN) * fmaxf(norms[j], EPSN)) * INV_T;
}

// Fused GEMM (C = fn * fn^T / T) + exp(C - 10) row-sum accumulation.
// 128x128 tile, BK=64, 8 waves (2x4, each 64x32 out), 16x16x32 bf16 MFMA.
// LDS tiles XOR-swizzled: byte c of row r stored at c ^ ((r&7)<<4).
// global_load_lds writes linearly, so the SOURCE address carries the inverse
// (same) swizzle; ds_read applies it on the read side (rule: both-sides).
__global__ __launch_bounds__(512) void gemm_lse(const unsigned short* __restrict__ fn,
                                                float* __restrict__ rowsum) {
  __shared__ unsigned short As[2][128 * 64];
  __shared__ unsigned short Bs[2][128 * 64];
  __shared__ float lrow[128];
  int tid = threadIdx.x;
  int wave = tid >> 6, lane = tid & 63;
  int wm = wave >> 2, wn = wave & 3;
  int hi = lane >> 4, lo = lane & 15;
  int bm = blockIdx.x >> 6, bn = blockIdx.x & 63;

  if (tid < 128) lrow[tid] = 0.0f;

  f32x4 acc[4][2];
#pragma unroll
  for (int m = 0; m < 4; ++m)
#pragma unroll
    for (int n = 0; n < 2; ++n) acc[m][n] = (f32x4){0.f, 0.f, 0.f, 0.f};

  const char* fb = (const char*)fn;

  // Staging: whole block covers one 128x64 tile (16 KB) in 2 insts x 512 lanes x 16B.
  auto stage = [&](int buf, int kt) {
    int k0b = kt * 128;  // byte offset along K (BK*2)
#pragma unroll
    for (int inst = 0; inst < 2; ++inst) {
      int o = tid * 16 + inst * 8192;      // linear LDS byte offset
      int r = o >> 7;                      // tile row
      int cs = (o & 127) ^ ((r & 7) << 4); // pre-swizzled source column byte
      const char* ga = fb + (size_t)(bm * 128 + r) * (D * 2) + k0b + cs;
      const char* gb = fb + (size_t)(bn * 128 + r) * (D * 2) + k0b + cs;
      async16((char*)&As[buf][0] + o, ga);
      async16((char*)&Bs[buf][0] + o, gb);
    }
  };

  auto compute = [&](int buf) {
#pragma unroll
    for (int ks = 0; ks < 2; ++ks) {
      int cbyte = ks * 64 + hi * 16;  // 16B-aligned column byte
      short8 af[4], bfr[2];
#pragma unroll
      for (int m = 0; m < 4; ++m) {
        int R = wm * 64 + m * 16 + lo;
        af[m] = *(const short8*)((const char*)&As[buf][0] + R * 128 +
                                 (cbyte ^ ((R & 7) << 4)));
      }
#pragma unroll
      for (int n = 0; n < 2; ++n) {
        int R = wn * 32 + n * 16 + lo;
        bfr[n] = *(const short8*)((const char*)&Bs[buf][0] + R * 128 +
                                  (cbyte ^ ((R & 7) << 4)));
      }
#pragma unroll
      for (int m = 0; m < 4; ++m)
#pragma unroll
        for (int n = 0; n < 2; ++n)
          acc[m][n] = __builtin_amdgcn_mfma_f32_16x16x32_bf16(af[m], bfr[n],
                                                              acc[m][n], 0, 0, 0);
    }
  };

  // 2-phase double-buffered pipeline: stage(t+1) issued BEFORE compute(t),
  // one full barrier (drains vmcnt) per K-tile.
  stage(0, 0);
  __syncthreads();
#pragma unroll
  for (int kt = 0; kt < 4; ++kt) {
    int cur = kt & 1;
    if (kt < 3) stage(cur ^ 1, kt + 1);
    compute(cur);
    __syncthreads();
  }

  // Epilogue: e = exp(sim/T - 10), skip true diagonal, per-row reduce.
  // C frag layout: col = lane&15, row = (lane>>4)*4 + reg.
#pragma unroll
  for (int m = 0; m < 4; ++m) {
#pragma unroll
    for (int j = 0; j < 4; ++j) {
      int lr = wm * 64 + m * 16 + hi * 4 + j;
      int grow = bm * 128 + lr;
      float v = 0.f;
#pragma unroll
      for (int n = 0; n < 2; ++n) {
        int gcol = bn * 128 + wn * 32 + n * 16 + lo;
        float e = __expf(acc[m][n][j] * INV_T - 10.0f);
        v += (grow == gcol) ? 0.f : e;
      }
#pragma unroll
      for (int off = 1; off < 16; off <<= 1) v += __shfl_xor(v, off, 64);
      if (lo == 0) atomicAdd(&lrow[lr], v);
    }
  }
  __syncthreads();
  if (tid < 128) atomicAdd(&rowsum[bm * 128 + tid], lrow[tid]);
}

__global__ __launch_bounds__(256) void final_k(const float* __restrict__ rowsum,
                                               const float* __restrict__ pos,
                                               float* __restrict__ out) {
  int tid = threadIdx.x;
  float s = 0.f;
  for (int i = tid; i < N; i += 256) s += 10.0f + logf(rowsum[i]) - pos[i];
#pragma unroll
  for (int off = 32; off; off >>= 1) s += __shfl_xor(s, off, 64);
  __shared__ float red[4];
  if ((tid & 63) == 0) red[tid >> 6] = s;
  __syncthreads();
  if (tid == 0) out[0] = (red[0] + red[1] + red[2] + red[3]) * (1.0f / N);
}

extern "C" void kernel_launch(void* const* d_in, const int* in_sizes, int n_in,
                              void* d_out, int out_size, void* d_ws, size_t ws_size,
                              hipStream_t stream) {
  const float* feats = (const float*)d_in[0];
  float* out = (float*)d_out;
  char* ws = (char*)d_ws;
  unsigned short* fn = (unsigned short*)ws;                    // 4 MB bf16 normalized feats
  float* norms = (float*)(ws + 4 * 1024 * 1024);               // 32 KB
  float* pos = (float*)(ws + 4 * 1024 * 1024 + 32 * 1024);     // 32 KB
  float* rowsum = (float*)(ws + 4 * 1024 * 1024 + 64 * 1024);  // 32 KB

  normalize_k<<<N / 4, 256, 0, stream>>>(feats, fn, norms, rowsum);
  pos_k<<<N / 4, 256, 0, stream>>>(feats, norms, pos);
  gemm_lse<<<64 * 64, 512, 0, stream>>>(fn, rowsum);
  final_k<<<1, 256, 0, stream>>>(rowsum, pos, out);
}

// Round 3
// 65.297 us; speedup vs baseline: 1.6770x; 1.4214x over previous
//
#include <hip/hip_runtime.h>
#include <hip/hip_bf16.h>
#include <math.h>

typedef __attribute__((ext_vector_type(8))) short short8;
typedef __attribute__((ext_vector_type(4))) float f32x4;

#define N 8192
#define D 256
#define INV_T 10.0f
#define EPSN 1e-8f

__device__ __forceinline__ unsigned short f2bf(float x) {
  unsigned int u = __float_as_uint(x);
  u += 0x7fffu + ((u >> 16) & 1u);
  return (unsigned short)(u >> 16);
}

__device__ __forceinline__ void async16(void* lds, const void* g) {
  __builtin_amdgcn_global_load_lds(
      (const __attribute__((address_space(1))) void*)g,
      (__attribute__((address_space(3))) void*)lds,
      16, 0, 0);
}

// One wave per row i: fp32 norms of i and j=(i+N/2)%N, bf16 normalized row i,
// pos[i] = cos(i,j)/T in fp32. Also zeroes rowsum.
__global__ __launch_bounds__(256) void normalize_pos_k(const float* __restrict__ feats,
                                                       unsigned short* __restrict__ fn,
                                                       float* __restrict__ pos,
                                                       float* __restrict__ rowsum) {
  int i = blockIdx.x * 4 + (threadIdx.x >> 6);
  int lane = threadIdx.x & 63;
  if (threadIdx.x < 4) rowsum[blockIdx.x * 4 + threadIdx.x] = 0.0f;
  int j = (i + (N / 2)) & (N - 1);
  float4 a = ((const float4*)(feats + (size_t)i * D))[lane];
  float4 b = ((const float4*)(feats + (size_t)j * D))[lane];
  float sa = a.x * a.x + a.y * a.y + a.z * a.z + a.w * a.w;
  float sb = b.x * b.x + b.y * b.y + b.z * b.z + b.w * b.w;
  float dt = a.x * b.x + a.y * b.y + a.z * b.z + a.w * b.w;
#pragma unroll
  for (int off = 32; off; off >>= 1) {
    sa += __shfl_xor(sa, off, 64);
    sb += __shfl_xor(sb, off, 64);
    dt += __shfl_xor(dt, off, 64);
  }
  float na = sqrtf(sa), nb = sqrtf(sb);
  float inv = 1.0f / fmaxf(na, EPSN);
  uint2 o;
  o.x = (unsigned)f2bf(a.x * inv) | ((unsigned)f2bf(a.y * inv) << 16);
  o.y = (unsigned)f2bf(a.z * inv) | ((unsigned)f2bf(a.w * inv) << 16);
  ((uint2*)(fn + (size_t)i * D))[lane] = o;
  if (lane == 0)
    pos[i] = dt / (fmaxf(na, EPSN) * fmaxf(nb, EPSN)) * INV_T;
}

// Fused symmetric GEMM (C = fn * fn^T / T) + exp(C - 10) row-sum accumulation.
// Upper-triangle blocks only (bm <= bn): off-diagonal blocks contribute both a
// row-reduce (bm panel) and, by symmetry, a col-reduce (bn panel).
// 128x128 tile, BK=64, 8 waves (2x4, each 64x32 out), 16x16x32 bf16 MFMA.
// LDS XOR-swizzled both-sides (pre-swizzled global_load_lds source + swizzled
// ds_read), 2-phase double-buffered.
__global__ __launch_bounds__(512) void gemm_lse(const unsigned short* __restrict__ fn,
                                                float* __restrict__ rowsum) {
  __shared__ unsigned short As[2][128 * 64];
  __shared__ unsigned short Bs[2][128 * 64];
  __shared__ float lrow[128];
  __shared__ float lcol[128];
  int tid = threadIdx.x;
  int wave = tid >> 6, lane = tid & 63;
  int wm = wave >> 2, wn = wave & 3;
  int hi = lane >> 4, lo = lane & 15;

  // Triangular block mapping: t -> (bm, bn), bm <= bn, row bm holds 64-bm blocks.
  int t = blockIdx.x;
  int bm = (int)((129.0 - sqrt((double)(16641 - 8 * t))) * 0.5);
  int S = bm * (129 - bm) / 2;
  if (t < S) { --bm; S = bm * (129 - bm) / 2; }
  else { int S1 = (bm + 1) * (128 - bm) / 2; if (t >= S1) { ++bm; S = S1; } }
  int bn = bm + (t - S);

  if (tid < 128) { lrow[tid] = 0.0f; lcol[tid] = 0.0f; }

  f32x4 acc[4][2];
#pragma unroll
  for (int m = 0; m < 4; ++m)
#pragma unroll
    for (int n = 0; n < 2; ++n) acc[m][n] = (f32x4){0.f, 0.f, 0.f, 0.f};

  const char* fb = (const char*)fn;

  auto stage = [&](int buf, int kt) {
    int k0b = kt * 128;  // byte offset along K (BK*2)
#pragma unroll
    for (int inst = 0; inst < 2; ++inst) {
      int o = tid * 16 + inst * 8192;      // linear LDS byte offset
      int r = o >> 7;                      // tile row
      int cs = (o & 127) ^ ((r & 7) << 4); // pre-swizzled source column byte
      const char* ga = fb + (size_t)(bm * 128 + r) * (D * 2) + k0b + cs;
      const char* gb = fb + (size_t)(bn * 128 + r) * (D * 2) + k0b + cs;
      async16((char*)&As[buf][0] + o, ga);
      async16((char*)&Bs[buf][0] + o, gb);
    }
  };

  auto compute = [&](int buf) {
#pragma unroll
    for (int ks = 0; ks < 2; ++ks) {
      int cbyte = ks * 64 + hi * 16;  // 16B-aligned column byte
      short8 af[4], bfr[2];
#pragma unroll
      for (int m = 0; m < 4; ++m) {
        int R = wm * 64 + m * 16 + lo;
        af[m] = *(const short8*)((const char*)&As[buf][0] + R * 128 +
                                 (cbyte ^ ((R & 7) << 4)));
      }
#pragma unroll
      for (int n = 0; n < 2; ++n) {
        int R = wn * 32 + n * 16 + lo;
        bfr[n] = *(const short8*)((const char*)&Bs[buf][0] + R * 128 +
                                  (cbyte ^ ((R & 7) << 4)));
      }
#pragma unroll
      for (int m = 0; m < 4; ++m)
#pragma unroll
        for (int n = 0; n < 2; ++n)
          acc[m][n] = __builtin_amdgcn_mfma_f32_16x16x32_bf16(af[m], bfr[n],
                                                              acc[m][n], 0, 0, 0);
    }
  };

  stage(0, 0);
  __syncthreads();
#pragma unroll
  for (int kt = 0; kt < 4; ++kt) {
    int cur = kt & 1;
    if (kt < 3) stage(cur ^ 1, kt + 1);
    compute(cur);
    __syncthreads();
  }

  // Epilogue: e = exp(sim/T - 10); diag masked; row-reduce always, col-reduce
  // (symmetric contribution to bn panel) when bm != bn.
  // C frag layout: col = lane&15, row = (lane>>4)*4 + reg.
  float ca[2] = {0.f, 0.f};
#pragma unroll
  for (int m = 0; m < 4; ++m) {
#pragma unroll
    for (int j = 0; j < 4; ++j) {
      int lr = wm * 64 + m * 16 + hi * 4 + j;
      int grow = bm * 128 + lr;
      float v = 0.f;
#pragma unroll
      for (int n = 0; n < 2; ++n) {
        int gcol = bn * 128 + wn * 32 + n * 16 + lo;
        float e = __expf(acc[m][n][j] * INV_T - 10.0f);
        e = (grow == gcol) ? 0.f : e;
        v += e;
        ca[n] += e;
      }
#pragma unroll
      for (int off = 1; off < 16; off <<= 1) v += __shfl_xor(v, off, 64);
      if (lo == 0) atomicAdd(&lrow[lr], v);
    }
  }
  if (bm != bn) {
#pragma unroll
    for (int n = 0; n < 2; ++n) {
      float c = ca[n];
      c += __shfl_xor(c, 16, 64);
      c += __shfl_xor(c, 32, 64);
      if (hi == 0) atomicAdd(&lcol[wn * 32 + n * 16 + lo], c);
    }
  }
  __syncthreads();
  if (tid < 128) {
    atomicAdd(&rowsum[bm * 128 + tid], lrow[tid]);
    if (bm != bn) atomicAdd(&rowsum[bn * 128 + tid], lcol[tid]);
  }
}

__global__ __launch_bounds__(256) void final_k(const float* __restrict__ rowsum,
                                               const float* __restrict__ pos,
                                               float* __restrict__ out) {
  int tid = threadIdx.x;
  float s = 0.f;
  for (int i = tid; i < N; i += 256) s += 10.0f + logf(rowsum[i]) - pos[i];
#pragma unroll
  for (int off = 32; off; off >>= 1) s += __shfl_xor(s, off, 64);
  __shared__ float red[4];
  if ((tid & 63) == 0) red[tid >> 6] = s;
  __syncthreads();
  if (tid == 0) out[0] = (red[0] + red[1] + red[2] + red[3]) * (1.0f / N);
}

extern "C" void kernel_launch(void* const* d_in, const int* in_sizes, int n_in,
                              void* d_out, int out_size, void* d_ws, size_t ws_size,
                              hipStream_t stream) {
  const float* feats = (const float*)d_in[0];
  float* out = (float*)d_out;
  char* ws = (char*)d_ws;
  unsigned short* fn = (unsigned short*)ws;                    // 4 MB bf16 normalized feats
  float* pos = (float*)(ws + 4 * 1024 * 1024);                 // 32 KB
  float* rowsum = (float*)(ws + 4 * 1024 * 1024 + 32 * 1024);  // 32 KB

  normalize_pos_k<<<N / 4, 256, 0, stream>>>(feats, fn, pos, rowsum);
  gemm_lse<<<(64 * 65) / 2, 512, 0, stream>>>(fn, rowsum);
  final_k<<<1, 256, 0, stream>>>(rowsum, pos, out);
}

// Round 4
// 59.093 us; speedup vs baseline: 1.8531x; 1.1050x over previous
//
#include <hip/hip_runtime.h>
#include <hip/hip_bf16.h>
#include <math.h>

typedef __attribute__((ext_vector_type(8))) short short8;
typedef __attribute__((ext_vector_type(4))) float f32x4;

#define N 8192
#define D 256
#define INV_T 10.0f
#define EPSN 1e-8f

__device__ __forceinline__ unsigned short f2bf(float x) {
  unsigned int u = __float_as_uint(x);
  u += 0x7fffu + ((u >> 16) & 1u);
  return (unsigned short)(u >> 16);
}

__device__ __forceinline__ void async16(void* lds, const void* g) {
  __builtin_amdgcn_global_load_lds(
      (const __attribute__((address_space(1))) void*)g,
      (__attribute__((address_space(3))) void*)lds,
      16, 0, 0);
}

// One wave per row: fp32 norm, bf16 normalized row. Also zeroes rowsum.
__global__ __launch_bounds__(256) void normalize_k(const float* __restrict__ feats,
                                                   unsigned short* __restrict__ fn,
                                                   float* __restrict__ rowsum) {
  int row = blockIdx.x * 4 + (threadIdx.x >> 6);
  int lane = threadIdx.x & 63;
  if (threadIdx.x < 4) rowsum[blockIdx.x * 4 + threadIdx.x] = 0.0f;
  float4 v = ((const float4*)(feats + (size_t)row * D))[lane];
  float ss = v.x * v.x + v.y * v.y + v.z * v.z + v.w * v.w;
#pragma unroll
  for (int off = 32; off; off >>= 1) ss += __shfl_xor(ss, off, 64);
  float inv = 1.0f / fmaxf(sqrtf(ss), EPSN);
  uint2 o;
  o.x = (unsigned)f2bf(v.x * inv) | ((unsigned)f2bf(v.y * inv) << 16);
  o.y = (unsigned)f2bf(v.z * inv) | ((unsigned)f2bf(v.w * inv) << 16);
  ((uint2*)(fn + (size_t)row * D))[lane] = o;
}

// Fused symmetric GEMM (C = fn*fn^T/T) + exp(C-10) row/col-sum + pos harvest.
// 256x256 tile, triangular blocks (bm<=bn), BK=64, 8 waves (2x4), each wave
// owns 128x64 output (8x4 16x16x32 frags). LDS XOR-swizzled both-sides,
// 2-phase double-buffered (stage issued before compute). Blocks bn==bm+16
// hold sim[i, i+4096] on their local diagonal -> write pos[] directly.
__global__ __launch_bounds__(512) void gemm_lse(const unsigned short* __restrict__ fn,
                                                float* __restrict__ rowsum,
                                                float* __restrict__ pos) {
  __shared__ unsigned short As[2][256 * 64];
  __shared__ unsigned short Bs[2][256 * 64];
  __shared__ float lrow[256];
  __shared__ float lcol[256];
  int tid = threadIdx.x;
  int wave = tid >> 6, lane = tid & 63;
  int wm = wave >> 2, wn = wave & 3;
  int hi = lane >> 4, lo = lane & 15;

  // Triangular mapping over 32 panels: t -> (bm, bn), bm <= bn.
  int t = blockIdx.x;
  int bm = (int)((65.0 - sqrt((double)(4225 - 8 * t))) * 0.5);
  int S = bm * (65 - bm) / 2;
  if (t < S) { --bm; S = bm * (65 - bm) / 2; }
  else { int S1 = (bm + 1) * (64 - bm) / 2; if (t >= S1) { ++bm; S = S1; } }
  int bn = bm + (t - S);

  const char* fb = (const char*)fn;

  auto stage = [&](int buf, int kt) {
    int k0b = kt * 128;  // byte offset along K (BK*2)
#pragma unroll
    for (int inst = 0; inst < 4; ++inst) {
      int o = tid * 16 + inst * 8192;      // linear LDS byte offset 0..32751
      int r = o >> 7;                      // tile row 0..255
      int cs = (o & 127) ^ ((r & 7) << 4); // pre-swizzled source column byte
      const char* ga = fb + (size_t)(bm * 256 + r) * (D * 2) + k0b + cs;
      const char* gb = fb + (size_t)(bn * 256 + r) * (D * 2) + k0b + cs;
      async16((char*)&As[buf][0] + o, ga);
      async16((char*)&Bs[buf][0] + o, gb);
    }
  };

  f32x4 acc[8][4];
#pragma unroll
  for (int m = 0; m < 8; ++m)
#pragma unroll
    for (int n = 0; n < 4; ++n) acc[m][n] = (f32x4){0.f, 0.f, 0.f, 0.f};

  auto compute = [&](int buf) {
#pragma unroll
    for (int ks = 0; ks < 2; ++ks) {
      int cbyte = ks * 64 + hi * 16;  // 16B-aligned column byte
      short8 af[8], bfr[4];
#pragma unroll
      for (int m = 0; m < 8; ++m) {
        int R = wm * 128 + m * 16 + lo;
        af[m] = *(const short8*)((const char*)&As[buf][0] + R * 128 +
                                 (cbyte ^ ((R & 7) << 4)));
      }
#pragma unroll
      for (int n = 0; n < 4; ++n) {
        int R = wn * 64 + n * 16 + lo;
        bfr[n] = *(const short8*)((const char*)&Bs[buf][0] + R * 128 +
                                  (cbyte ^ ((R & 7) << 4)));
      }
#pragma unroll
      for (int m = 0; m < 8; ++m)
#pragma unroll
        for (int n = 0; n < 4; ++n)
          acc[m][n] = __builtin_amdgcn_mfma_f32_16x16x32_bf16(af[m], bfr[n],
                                                              acc[m][n], 0, 0, 0);
    }
  };

  stage(0, 0);
  if (tid < 256) { lrow[tid] = 0.0f; lcol[tid] = 0.0f; }
  __syncthreads();
#pragma unroll
  for (int kt = 0; kt < 4; ++kt) {
    int cur = kt & 1;
    if (kt < 3) stage(cur ^ 1, kt + 1);
    compute(cur);
    __syncthreads();
  }

  // Epilogue. C frag layout: col = lane&15, row = (lane>>4)*4 + reg.
  float ca[4] = {0.f, 0.f, 0.f, 0.f};
#pragma unroll
  for (int m = 0; m < 8; ++m) {
#pragma unroll
    for (int j = 0; j < 4; ++j) {
      int lr = wm * 128 + m * 16 + hi * 4 + j;
      int grow = bm * 256 + lr;
      float v = 0.f;
#pragma unroll
      for (int n = 0; n < 4; ++n) {
        int gcol = bn * 256 + wn * 64 + n * 16 + lo;
        float e = __expf(acc[m][n][j] * INV_T - 10.0f);
        e = (grow == gcol) ? 0.f : e;
        v += e;
        ca[n] += e;
      }
#pragma unroll
      for (int off = 1; off < 16; off <<= 1) v += __shfl_xor(v, off, 64);
      if (lo == 0) atomicAdd(&lrow[lr], v);
    }
  }
  if (bm != bn) {
#pragma unroll
    for (int n = 0; n < 4; ++n) {
      float c = ca[n];
      c += __shfl_xor(c, 16, 64);
      c += __shfl_xor(c, 32, 64);
      if (hi == 0) atomicAdd(&lcol[wn * 64 + n * 16 + lo], c);
    }
  }
  // pos harvest: block (bm, bm+16) local diagonal = sim[i, i+4096].
  if (bn == bm + 16) {
#pragma unroll
    for (int m = 0; m < 8; ++m) {
      int rb = wm * 128 + m * 16;
#pragma unroll
      for (int n = 0; n < 4; ++n) {
        if (rb == wn * 64 + n * 16 && (lo >> 2) == hi) {
          int j = lo & 3;
          f32x4 a = acc[m][n];
          float pv = (j == 0) ? a[0] : (j == 1) ? a[1] : (j == 2) ? a[2] : a[3];
          pv *= INV_T;
          int gr = bm * 256 + rb + lo;
          pos[gr] = pv;
          pos[gr + N / 2] = pv;
        }
      }
    }
  }
  __syncthreads();
  if (tid < 256) {
    atomicAdd(&rowsum[bm * 256 + tid], lrow[tid]);
    if (bm != bn) atomicAdd(&rowsum[bn * 256 + tid], lcol[tid]);
  }
}

__global__ __launch_bounds__(1024) void final_k(const float* __restrict__ rowsum,
                                                const float* __restrict__ pos,
                                                float* __restrict__ out) {
  int tid = threadIdx.x;
  float s = 0.f;
  for (int i = tid; i < N; i += 1024) s += 10.0f + logf(rowsum[i]) - pos[i];
#pragma unroll
  for (int off = 32; off; off >>= 1) s += __shfl_xor(s, off, 64);
  __shared__ float red[16];
  if ((tid & 63) == 0) red[tid >> 6] = s;
  __syncthreads();
  if (tid == 0) {
    float tot = 0.f;
#pragma unroll
    for (int w = 0; w < 16; ++w) tot += red[w];
    out[0] = tot * (1.0f / N);
  }
}

extern "C" void kernel_launch(void* const* d_in, const int* in_sizes, int n_in,
                              void* d_out, int out_size, void* d_ws, size_t ws_size,
                              hipStream_t stream) {
  const float* feats = (const float*)d_in[0];
  float* out = (float*)d_out;
  char* ws = (char*)d_ws;
  unsigned short* fn = (unsigned short*)ws;                    // 4 MB bf16 normalized feats
  float* pos = (float*)(ws + 4 * 1024 * 1024);                 // 32 KB
  float* rowsum = (float*)(ws + 4 * 1024 * 1024 + 32 * 1024);  // 32 KB

  normalize_k<<<N / 4, 256, 0, stream>>>(feats, fn, rowsum);
  gemm_lse<<<(32 * 33) / 2, 512, 0, stream>>>(fn, rowsum, pos);
  final_k<<<1, 1024, 0, stream>>>(rowsum, pos, out);
}

// Round 5
// 56.094 us; speedup vs baseline: 1.9521x; 1.0535x over previous
//
#include <hip/hip_runtime.h>
#include <hip/hip_bf16.h>
#include <math.h>

typedef __attribute__((ext_vector_type(8))) short short8;
typedef __attribute__((ext_vector_type(4))) float f32x4;

#define N 8192
#define D 256
#define INV_T 10.0f
#define EPSN 1e-8f

__device__ __forceinline__ unsigned short f2bf(float x) {
  unsigned int u = __float_as_uint(x);
  u += 0x7fffu + ((u >> 16) & 1u);
  return (unsigned short)(u >> 16);
}

__device__ __forceinline__ void async16(void* lds, const void* g) {
  __builtin_amdgcn_global_load_lds(
      (const __attribute__((address_space(1))) void*)g,
      (__attribute__((address_space(3))) void*)lds,
      16, 0, 0);
}

// One wave per row: fp32 norm, bf16 normalized row. Also zeroes rowsum + out.
__global__ __launch_bounds__(256) void normalize_k(const float* __restrict__ feats,
                                                   unsigned short* __restrict__ fn,
                                                   float* __restrict__ rowsum,
                                                   float* __restrict__ out) {
  int row = blockIdx.x * 4 + (threadIdx.x >> 6);
  int lane = threadIdx.x & 63;
  if (threadIdx.x < 4) rowsum[blockIdx.x * 4 + threadIdx.x] = 0.0f;
  if (blockIdx.x == 0 && threadIdx.x == 0) out[0] = 0.0f;
  float4 v = ((const float4*)(feats + (size_t)row * D))[lane];
  float ss = v.x * v.x + v.y * v.y + v.z * v.z + v.w * v.w;
#pragma unroll
  for (int off = 32; off; off >>= 1) ss += __shfl_xor(ss, off, 64);
  float inv = 1.0f / fmaxf(sqrtf(ss), EPSN);
  uint2 o;
  o.x = (unsigned)f2bf(v.x * inv) | ((unsigned)f2bf(v.y * inv) << 16);
  o.y = (unsigned)f2bf(v.z * inv) | ((unsigned)f2bf(v.w * inv) << 16);
  ((uint2*)(fn + (size_t)row * D))[lane] = o;
}

// Fused symmetric GEMM (C = fn*fn^T/T) + exp(C-10) row/col-sum + pos harvest.
// 128x128 tile, triangular blocks (bm<=bn) over 64 panels, BK=64, 8 waves
// (2x4, each 64x32 out), 16x16x32 bf16 MFMA. LDS XOR-swizzled both-sides.
// Counted-vmcnt pipeline: prologue stages tiles 0,1; per step wait vmcnt(4)
// (own loads for current tile done, next tile stays IN FLIGHT), raw barrier,
// compute, lgkmcnt fence + raw barrier, then stage tile kt+2 into the buffer
// just consumed. Only the prologue exposes load latency.
__global__ __launch_bounds__(512) void gemm_lse(const unsigned short* __restrict__ fn,
                                                float* __restrict__ rowsum,
                                                float* __restrict__ pos) {
  __shared__ unsigned short As[2][128 * 64];
  __shared__ unsigned short Bs[2][128 * 64];
  __shared__ float lrow[128];
  __shared__ float lcol[128];
  int tid = threadIdx.x;
  int wave = tid >> 6, lane = tid & 63;
  int wm = wave >> 2, wn = wave & 3;
  int hi = lane >> 4, lo = lane & 15;

  // XCD-chunked triangular order: 2080 = 8 * 260, bijective.
  int b = blockIdx.x;
  int t = (b & 7) * 260 + (b >> 3);
  int bm = (int)((129.0 - sqrt((double)(16641 - 8 * t))) * 0.5);
  int S = bm * (129 - bm) / 2;
  if (t < S) { --bm; S = bm * (129 - bm) / 2; }
  else { int S1 = (bm + 1) * (128 - bm) / 2; if (t >= S1) { ++bm; S = S1; } }
  int bn = bm + (t - S);

  const char* fb = (const char*)fn;

  auto stage = [&](int buf, int kt) {
    int k0b = kt * 128;  // byte offset along K (BK*2)
#pragma unroll
    for (int inst = 0; inst < 2; ++inst) {
      int o = tid * 16 + inst * 8192;      // linear LDS byte offset
      int r = o >> 7;                      // tile row
      int cs = (o & 127) ^ ((r & 7) << 4); // pre-swizzled source column byte
      const char* ga = fb + (size_t)(bm * 128 + r) * (D * 2) + k0b + cs;
      const char* gb = fb + (size_t)(bn * 128 + r) * (D * 2) + k0b + cs;
      async16((char*)&As[buf][0] + o, ga);
      async16((char*)&Bs[buf][0] + o, gb);
    }
  };

  f32x4 acc[4][2];
#pragma unroll
  for (int m = 0; m < 4; ++m)
#pragma unroll
    for (int n = 0; n < 2; ++n) acc[m][n] = (f32x4){0.f, 0.f, 0.f, 0.f};

  auto compute = [&](int buf) {
#pragma unroll
    for (int ks = 0; ks < 2; ++ks) {
      int cbyte = ks * 64 + hi * 16;  // 16B-aligned column byte
      short8 af[4], bfr[2];
#pragma unroll
      for (int m = 0; m < 4; ++m) {
        int R = wm * 64 + m * 16 + lo;
        af[m] = *(const short8*)((const char*)&As[buf][0] + R * 128 +
                                 (cbyte ^ ((R & 7) << 4)));
      }
#pragma unroll
      for (int n = 0; n < 2; ++n) {
        int R = wn * 32 + n * 16 + lo;
        bfr[n] = *(const short8*)((const char*)&Bs[buf][0] + R * 128 +
                                  (cbyte ^ ((R & 7) << 4)));
      }
#pragma unroll
      for (int m = 0; m < 4; ++m)
#pragma unroll
        for (int n = 0; n < 2; ++n)
          acc[m][n] = __builtin_amdgcn_mfma_f32_16x16x32_bf16(af[m], bfr[n],
                                                              acc[m][n], 0, 0, 0);
    }
  };

  stage(0, 0);          // 4 loads/thread
  stage(1, 1);          // 4 more: 8 outstanding
  if (tid < 128) { lrow[tid] = 0.0f; lcol[tid] = 0.0f; }

#pragma unroll
  for (int kt = 0; kt < 4; ++kt) {
    if (kt < 3) asm volatile("s_waitcnt vmcnt(4)" ::: "memory");
    else        asm volatile("s_waitcnt vmcnt(0)" ::: "memory");
    __builtin_amdgcn_s_barrier();        // all waves' tile-kt loads landed
    __builtin_amdgcn_sched_barrier(0);   // pin ds_reads below the barrier
    compute(kt & 1);
    asm volatile("s_waitcnt lgkmcnt(0)" ::: "memory");  // own ds_reads done
    __builtin_amdgcn_sched_barrier(0);
    __builtin_amdgcn_s_barrier();        // WAR: everyone done reading buf
    if (kt < 2) stage(kt & 1, kt + 2);   // refill the buffer just consumed
  }

  // Epilogue. C frag layout: col = lane&15, row = (lane>>4)*4 + reg.
  float ca[2] = {0.f, 0.f};
#pragma unroll
  for (int m = 0; m < 4; ++m) {
#pragma unroll
    for (int j = 0; j < 4; ++j) {
      int lr = wm * 64 + m * 16 + hi * 4 + j;
      int grow = bm * 128 + lr;
      float v = 0.f;
#pragma unroll
      for (int n = 0; n < 2; ++n) {
        int gcol = bn * 128 + wn * 32 + n * 16 + lo;
        float e = __expf(acc[m][n][j] * INV_T - 10.0f);
        e = (grow == gcol) ? 0.f : e;
        v += e;
        ca[n] += e;
      }
#pragma unroll
      for (int off = 1; off < 16; off <<= 1) v += __shfl_xor(v, off, 64);
      if (lo == 0) atomicAdd(&lrow[lr], v);
    }
  }
  if (bm != bn) {
#pragma unroll
    for (int n = 0; n < 2; ++n) {
      float c = ca[n];
      c += __shfl_xor(c, 16, 64);
      c += __shfl_xor(c, 32, 64);
      if (hi == 0) atomicAdd(&lcol[wn * 32 + n * 16 + lo], c);
    }
  }
  // pos harvest: block (bm, bm+32) local diagonal = sim[i, i+4096].
  if (bn == bm + 32) {
#pragma unroll
    for (int m = 0; m < 4; ++m) {
      int rb = wm * 64 + m * 16;
#pragma unroll
      for (int n = 0; n < 2; ++n) {
        if (rb == wn * 32 + n * 16 && (lo >> 2) == hi) {
          int j = lo & 3;
          f32x4 a = acc[m][n];
          float pv = (j == 0) ? a[0] : (j == 1) ? a[1] : (j == 2) ? a[2] : a[3];
          pv *= INV_T;
          int gr = bm * 128 + rb + lo;
          pos[gr] = pv;
          pos[gr + N / 2] = pv;
        }
      }
    }
  }
  __syncthreads();
  if (tid < 128) {
    atomicAdd(&rowsum[bm * 128 + tid], lrow[tid]);
    if (bm != bn) atomicAdd(&rowsum[bn * 128 + tid], lcol[tid]);
  }
}

// 32 blocks x 256 threads: one row each, partial-reduce, atomic accumulate.
__global__ __launch_bounds__(256) void final_k(const float* __restrict__ rowsum,
                                               const float* __restrict__ pos,
                                               float* __restrict__ out) {
  int tid = threadIdx.x;
  int i = blockIdx.x * 256 + tid;
  float s = 10.0f + logf(rowsum[i]) - pos[i];
#pragma unroll
  for (int off = 32; off; off >>= 1) s += __shfl_xor(s, off, 64);
  __shared__ float red[4];
  if ((tid & 63) == 0) red[tid >> 6] = s;
  __syncthreads();
  if (tid == 0)
    atomicAdd(out, (red[0] + red[1] + red[2] + red[3]) * (1.0f / N));
}

extern "C" void kernel_launch(void* const* d_in, const int* in_sizes, int n_in,
                              void* d_out, int out_size, void* d_ws, size_t ws_size,
                              hipStream_t stream) {
  const float* feats = (const float*)d_in[0];
  float* out = (float*)d_out;
  char* ws = (char*)d_ws;
  unsigned short* fn = (unsigned short*)ws;                    // 4 MB bf16 normalized feats
  float* pos = (float*)(ws + 4 * 1024 * 1024);                 // 32 KB
  float* rowsum = (float*)(ws + 4 * 1024 * 1024 + 32 * 1024);  // 32 KB

  normalize_k<<<N / 4, 256, 0, stream>>>(feats, fn, rowsum, out);
  gemm_lse<<<(64 * 65) / 2, 512, 0, stream>>>(fn, rowsum, pos);
  final_k<<<32, 256, 0, stream>>>(rowsum, pos, out);
}

// Round 6
// 44.941 us; speedup vs baseline: 2.4366x; 1.2482x over previous
//
#include <hip/hip_runtime.h>
#include <hip/hip_bf16.h>
#include <math.h>

typedef __attribute__((ext_vector_type(8))) short short8;
typedef __attribute__((ext_vector_type(4))) float f32x4;

#define N 8192
#define D 256
#define INV_T 10.0f
#define EPSN 1e-8f

__device__ __forceinline__ unsigned short f2bf(float x) {
  unsigned int u = __float_as_uint(x);
  u += 0x7fffu + ((u >> 16) & 1u);
  return (unsigned short)(u >> 16);
}

__device__ __forceinline__ void async16(void* lds, const void* g) {
  __builtin_amdgcn_global_load_lds(
      (const __attribute__((address_space(1))) void*)g,
      (__attribute__((address_space(3))) void*)lds,
      16, 0, 0);
}

// Sum over each 16-lane group via DPP row_shr adds (VALU pipe, no DS traffic).
// Result valid in lane 15 of each group (lanes 15/31/47/63).
__device__ __forceinline__ float rowsum16(float v) {
  v += __uint_as_float(__builtin_amdgcn_update_dpp(
      0u, __float_as_uint(v), 0x118, 0xf, 0xf, true));  // row_shr:8
  v += __uint_as_float(__builtin_amdgcn_update_dpp(
      0u, __float_as_uint(v), 0x114, 0xf, 0xf, true));  // row_shr:4
  v += __uint_as_float(__builtin_amdgcn_update_dpp(
      0u, __float_as_uint(v), 0x112, 0xf, 0xf, true));  // row_shr:2
  v += __uint_as_float(__builtin_amdgcn_update_dpp(
      0u, __float_as_uint(v), 0x111, 0xf, 0xf, true));  // row_shr:1
  return v;
}

// One wave per row: fp32 norm, bf16 normalized row. Also zeroes rowsum + out.
__global__ __launch_bounds__(256) void normalize_k(const float* __restrict__ feats,
                                                   unsigned short* __restrict__ fn,
                                                   float* __restrict__ rowsum,
                                                   float* __restrict__ out) {
  int row = blockIdx.x * 4 + (threadIdx.x >> 6);
  int lane = threadIdx.x & 63;
  if (threadIdx.x < 4) rowsum[blockIdx.x * 4 + threadIdx.x] = 0.0f;
  if (blockIdx.x == 0 && threadIdx.x == 0) out[0] = 0.0f;
  float4 v = ((const float4*)(feats + (size_t)row * D))[lane];
  float ss = v.x * v.x + v.y * v.y + v.z * v.z + v.w * v.w;
#pragma unroll
  for (int off = 32; off; off >>= 1) ss += __shfl_xor(ss, off, 64);
  float inv = 1.0f / fmaxf(sqrtf(ss), EPSN);
  uint2 o;
  o.x = (unsigned)f2bf(v.x * inv) | ((unsigned)f2bf(v.y * inv) << 16);
  o.y = (unsigned)f2bf(v.z * inv) | ((unsigned)f2bf(v.w * inv) << 16);
  ((uint2*)(fn + (size_t)row * D))[lane] = o;
}

// Fused symmetric GEMM (C = fn*fn^T/T) + exp(C-10) row/col-sum + pos harvest.
// 128x128 tile, triangular blocks (bm<=bn), BK=64, 8 waves (2x4, each 64x32),
// 16x16x32 bf16 MFMA. LDS XOR-swizzled both-sides; counted-vmcnt pipeline
// (next tile stays in flight across the barrier). Row-reduce via DPP (VALU),
// not shfl (DS) -- the DS pipe is the CU-shared bottleneck.
__global__ __launch_bounds__(512) void gemm_lse(const unsigned short* __restrict__ fn,
                                                float* __restrict__ rowsum,
                                                float* __restrict__ pos) {
  __shared__ unsigned short As[2][128 * 64];
  __shared__ unsigned short Bs[2][128 * 64];
  __shared__ float lrow[128];
  __shared__ float lcol[128];
  int tid = threadIdx.x;
  int wave = tid >> 6, lane = tid & 63;
  int wm = wave >> 2, wn = wave & 3;
  int hi = lane >> 4, lo = lane & 15;

  // XCD-chunked triangular order: 2080 = 8 * 260, bijective.
  int b = blockIdx.x;
  int t = (b & 7) * 260 + (b >> 3);
  int bm = (int)((129.0 - sqrt((double)(16641 - 8 * t))) * 0.5);
  int S = bm * (129 - bm) / 2;
  if (t < S) { --bm; S = bm * (129 - bm) / 2; }
  else { int S1 = (bm + 1) * (128 - bm) / 2; if (t >= S1) { ++bm; S = S1; } }
  int bn = bm + (t - S);

  const char* fb = (const char*)fn;

  auto stage = [&](int buf, int kt) {
    int k0b = kt * 128;  // byte offset along K (BK*2)
#pragma unroll
    for (int inst = 0; inst < 2; ++inst) {
      int o = tid * 16 + inst * 8192;      // linear LDS byte offset
      int r = o >> 7;                      // tile row
      int cs = (o & 127) ^ ((r & 7) << 4); // pre-swizzled source column byte
      const char* ga = fb + (size_t)(bm * 128 + r) * (D * 2) + k0b + cs;
      const char* gb = fb + (size_t)(bn * 128 + r) * (D * 2) + k0b + cs;
      async16((char*)&As[buf][0] + o, ga);
      async16((char*)&Bs[buf][0] + o, gb);
    }
  };

  f32x4 acc[4][2];
#pragma unroll
  for (int m = 0; m < 4; ++m)
#pragma unroll
    for (int n = 0; n < 2; ++n) acc[m][n] = (f32x4){0.f, 0.f, 0.f, 0.f};

  auto compute = [&](int buf) {
#pragma unroll
    for (int ks = 0; ks < 2; ++ks) {
      int cbyte = ks * 64 + hi * 16;  // 16B-aligned column byte
      short8 af[4], bfr[2];
#pragma unroll
      for (int m = 0; m < 4; ++m) {
        int R = wm * 64 + m * 16 + lo;
        af[m] = *(const short8*)((const char*)&As[buf][0] + R * 128 +
                                 (cbyte ^ ((R & 7) << 4)));
      }
#pragma unroll
      for (int n = 0; n < 2; ++n) {
        int R = wn * 32 + n * 16 + lo;
        bfr[n] = *(const short8*)((const char*)&Bs[buf][0] + R * 128 +
                                  (cbyte ^ ((R & 7) << 4)));
      }
#pragma unroll
      for (int m = 0; m < 4; ++m)
#pragma unroll
        for (int n = 0; n < 2; ++n)
          acc[m][n] = __builtin_amdgcn_mfma_f32_16x16x32_bf16(af[m], bfr[n],
                                                              acc[m][n], 0, 0, 0);
    }
  };

  stage(0, 0);          // 4 loads/thread
  stage(1, 1);          // 4 more: 8 outstanding
  if (tid < 128) { lrow[tid] = 0.0f; lcol[tid] = 0.0f; }

#pragma unroll
  for (int kt = 0; kt < 4; ++kt) {
    if (kt < 3) asm volatile("s_waitcnt vmcnt(4)" ::: "memory");
    else        asm volatile("s_waitcnt vmcnt(0)" ::: "memory");
    __builtin_amdgcn_s_barrier();        // all waves' tile-kt loads landed
    __builtin_amdgcn_sched_barrier(0);   // pin ds_reads below the barrier
    compute(kt & 1);
    asm volatile("s_waitcnt lgkmcnt(0)" ::: "memory");  // own ds_reads done
    __builtin_amdgcn_sched_barrier(0);
    __builtin_amdgcn_s_barrier();        // WAR: everyone done reading buf
    if (kt < 2) stage(kt & 1, kt + 2);   // refill the buffer just consumed
  }

  // Epilogue. C frag layout: col = lane&15, row = (lane>>4)*4 + reg.
  bool isdiag = (bm == bn);
  float ca[2] = {0.f, 0.f};
  int rbase = wm * 64, cbase = wn * 32;
#pragma unroll
  for (int m = 0; m < 4; ++m) {
#pragma unroll
    for (int j = 0; j < 4; ++j) {
      int rloc = rbase + m * 16 + hi * 4 + j;
      float v = 0.f;
#pragma unroll
      for (int n = 0; n < 2; ++n) {
        float e = __expf(fmaf(acc[m][n][j], 10.0f, -10.0f));
        if (isdiag && rloc == cbase + n * 16 + lo) e = 0.f;
        v += e;
        ca[n] += e;
      }
      v = rowsum16(v);  // DPP: VALU pipe, no DS traffic
      if (lo == 15) atomicAdd(&lrow[rloc], v);
    }
  }
  if (!isdiag) {
#pragma unroll
    for (int n = 0; n < 2; ++n) {
      float c = ca[n];
      c += __shfl_xor(c, 16, 64);
      c += __shfl_xor(c, 32, 64);
      if (hi == 0) atomicAdd(&lcol[cbase + n * 16 + lo], c);
    }
  }
  // pos harvest: block (bm, bm+32) local diagonal = sim[i, i+4096].
  if (bn == bm + 32) {
#pragma unroll
    for (int m = 0; m < 4; ++m) {
      int rb = wm * 64 + m * 16;
#pragma unroll
      for (int n = 0; n < 2; ++n) {
        if (rb == wn * 32 + n * 16 && (lo >> 2) == hi) {
          int j = lo & 3;
          f32x4 a = acc[m][n];
          float pv = (j == 0) ? a[0] : (j == 1) ? a[1] : (j == 2) ? a[2] : a[3];
          pv *= INV_T;
          int gr = bm * 128 + rb + lo;
          pos[gr] = pv;
          pos[gr + N / 2] = pv;
        }
      }
    }
  }
  __syncthreads();
  if (tid < 128) {
    atomicAdd(&rowsum[bm * 128 + tid], lrow[tid]);
    if (!isdiag) atomicAdd(&rowsum[bn * 128 + tid], lcol[tid]);
  }
}

// 32 blocks x 256 threads: one row each, partial-reduce, atomic accumulate.
__global__ __launch_bounds__(256) void final_k(const float* __restrict__ rowsum,
                                               const float* __restrict__ pos,
                                               float* __restrict__ out) {
  int tid = threadIdx.x;
  int i = blockIdx.x * 256 + tid;
  float s = 10.0f + logf(rowsum[i]) - pos[i];
#pragma unroll
  for (int off = 32; off; off >>= 1) s += __shfl_xor(s, off, 64);
  __shared__ float red[4];
  if ((tid & 63) == 0) red[tid >> 6] = s;
  __syncthreads();
  if (tid == 0)
    atomicAdd(out, (red[0] + red[1] + red[2] + red[3]) * (1.0f / N));
}

extern "C" void kernel_launch(void* const* d_in, const int* in_sizes, int n_in,
                              void* d_out, int out_size, void* d_ws, size_t ws_size,
                              hipStream_t stream) {
  const float* feats = (const float*)d_in[0];
  float* out = (float*)d_out;
  char* ws = (char*)d_ws;
  unsigned short* fn = (unsigned short*)ws;                    // 4 MB bf16 normalized feats
  float* pos = (float*)(ws + 4 * 1024 * 1024);                 // 32 KB
  float* rowsum = (float*)(ws + 4 * 1024 * 1024 + 32 * 1024);  // 32 KB

  normalize_k<<<N / 4, 256, 0, stream>>>(feats, fn, rowsum, out);
  gemm_lse<<<(64 * 65) / 2, 512, 0, stream>>>(fn, rowsum, pos);
  final_k<<<32, 256, 0, stream>>>(rowsum, pos, out);
}